// Round 3
// baseline (1414.108 us; speedup 1.0000x reference)
//
#include <hip/hip_runtime.h>
#include <stdint.h>

#define NB 8192
#define ND 128
#define NK 32768
#define NTOP 8
#define ROWS_PER_BLOCK 32
#define NTHREADS 512
#define NWAVES 8
#define ROWS_PER_WAVE 4
#define CHUNK 512
#define NCHUNK (NK / CHUNK)   // 64
#define CT_PITCH 514          // 512 + 2 pad floats: stride % 32 == 2 -> 2-way (free)

__device__ __forceinline__ uint32_t mono_f32(float f) {
    uint32_t u = __float_as_uint(f);
    return (u & 0x80000000u) ? ~u : (u | 0x80000000u);
}
__device__ __forceinline__ float unmono_f32(uint32_t h) {
    uint32_t u = (h & 0x80000000u) ? (h & 0x7fffffffu) : ~h;
    return __uint_as_float(u);
}
__device__ __forceinline__ uint64_t u64min(uint64_t a, uint64_t b) { return a < b ? a : b; }
__device__ __forceinline__ uint64_t u64max(uint64_t a, uint64_t b) { return a > b ? a : b; }

__global__ __launch_bounds__(NTHREADS, 1)
void vq_main(const float* __restrict__ z, const float* __restrict__ cb,
             float* __restrict__ out, double* __restrict__ loss_acc)
{
    __shared__ float  zs[ROWS_PER_BLOCK][ND];   // 16 KB
    __shared__ float  ct[32 * CT_PITCH];        // 64.25 KB, [d within quarter][code]
    __shared__ float  A_s[ROWS_PER_BLOCK];

    const int tid  = threadIdx.x;
    const int lane = tid & 63;
    const int wid  = tid >> 6;
    const int row0 = blockIdx.x * ROWS_PER_BLOCK;

    // ---- stage z tile (coalesced) ----
    #pragma unroll
    for (int i = 0; i < (ROWS_PER_BLOCK * ND) / NTHREADS; ++i) {
        int e = tid + i * NTHREADS;
        zs[e >> 7][e & 127] = z[(size_t)(row0 + (e >> 7)) * ND + (e & 127)];
    }
    __syncthreads();

    // ---- A = numpy-pairwise f32 sum of z*z (bit-exact np.sum replication) ----
    // n=128 <= PW_BLOCKSIZE: 8 accumulators r[j] = sum of a[j+8i] (sequential),
    // combine ((r0+r1)+(r2+r3))+((r4+r5)+(r6+r7)); a_i = fl32(z_i*z_i) pre-rounded.
    if (lane < ROWS_PER_WAVE) {
        const int lrow = wid * ROWS_PER_WAVE + lane;
        float rr[8];
        #pragma unroll
        for (int j = 0; j < 8; ++j) {
            float v = zs[lrow][j];
            float p = v * v;
            asm volatile("" : "+v"(p));   // block fma contraction: a_i rounds first
            rr[j] = p;
        }
        #pragma unroll
        for (int i = 8; i < 128; i += 8) {
            #pragma unroll
            for (int j = 0; j < 8; ++j) {
                float v = zs[lrow][i + j];
                float p = v * v;
                asm volatile("" : "+v"(p));
                rr[j] += p;
            }
        }
        A_s[lrow] = ((rr[0] + rr[1]) + (rr[2] + rr[3])) + ((rr[4] + rr[5]) + (rr[6] + rr[7]));
    }
    __syncthreads();

    // running top-16 (UNSORTED): lane holds one entry of wave-local row (lane>>4)'s set
    uint64_t ent = ~0ull;       // sentinel = +inf
    const int rloc = lane >> 4;

    for (int kc = 0; kc < NCHUNK; ++kc) {
        const int k0 = kc * CHUNK;
        float acc[ROWS_PER_WAVE][8];
        #pragma unroll
        for (int r = 0; r < ROWS_PER_WAVE; ++r)
            #pragma unroll
            for (int j = 0; j < 8; ++j) acc[r][j] = 0.f;

        for (int q = 0; q < 4; ++q) {
            __syncthreads();   // previous quarter's readers done
            // stage 512 codes x 32 dims, transposed into ct[d][code]
            #pragma unroll
            for (int i = 0; i < 8; ++i) {
                int e4   = tid + i * NTHREADS;   // 0..4095 float4s
                int code = e4 >> 3;              // 0..511
                int d4   = e4 & 7;               // float4 within 32-d quarter
                const float4 v = *reinterpret_cast<const float4*>(
                    &cb[(size_t)(k0 + code) * ND + q * 32 + d4 * 4]);
                ct[(d4 * 4 + 0) * CT_PITCH + code] = v.x;
                ct[(d4 * 4 + 1) * CT_PITCH + code] = v.y;
                ct[(d4 * 4 + 2) * CT_PITCH + code] = v.z;
                ct[(d4 * 4 + 3) * CT_PITCH + code] = v.w;
            }
            __syncthreads();
            // compute: lane's codes = 2*lane + (j&1) + 128*(j>>1)
            // dot accumulated as a SEQUENTIAL FMA CHAIN in ascending d order
            // (replicates BLAS sgemm microkernel per-element k-chain, init 0).
            #pragma unroll 8
            for (int d = 0; d < 32; ++d) {
                float zv[ROWS_PER_WAVE];
                #pragma unroll
                for (int r = 0; r < ROWS_PER_WAVE; ++r)
                    zv[r] = zs[wid * ROWS_PER_WAVE + r][q * 32 + d];  // uniform broadcast
                #pragma unroll
                for (int jp = 0; jp < 4; ++jp) {
                    float2 cv = *reinterpret_cast<const float2*>(
                        &ct[d * CT_PITCH + 2 * lane + 128 * jp]);
                    #pragma unroll
                    for (int r = 0; r < ROWS_PER_WAVE; ++r) {
                        acc[r][2 * jp + 0] = __builtin_fmaf(zv[r], cv.x, acc[r][2 * jp + 0]);
                        acc[r][2 * jp + 1] = __builtin_fmaf(zv[r], cv.y, acc[r][2 * jp + 1]);
                    }
                }
            }
        }

        // ---- merge chunk candidates into running top-16 (per wave-row) ----
        // key = (mono(fl32(A - 2*dot)) << 32) | code : ascending u64 ==
        // (d ascending, index ascending) == reference stable ranking incl. f32 ties.
        for (int r = 0; r < ROWS_PER_WAVE; ++r) {
            const float Ar = A_s[wid * ROWS_PER_WAVE + r];
            uint64_t kk[8];
            #pragma unroll
            for (int j = 0; j < 8; ++j) {
                int code = k0 + 2 * lane + (j & 1) + 128 * (j >> 1);
                float qv = Ar - 2.0f * acc[r][j];   // fl32, round-half-even like host
                kk[j] = ((uint64_t)mono_f32(qv) << 32) | (uint32_t)code;
            }
            uint64_t lmin = kk[0];
            #pragma unroll
            for (int j = 1; j < 8; ++j) lmin = u64min(lmin, kk[j]);

            while (true) {
                uint64_t m = lmin;
                #pragma unroll
                for (int s = 1; s < 64; s <<= 1)
                    m = u64min(m, (uint64_t)__shfl_xor((unsigned long long)m, s, 64));
                uint64_t w = ent;
                #pragma unroll
                for (int s = 1; s < 16; s <<= 1)
                    w = u64max(w, (uint64_t)__shfl_xor((unsigned long long)w, s, 64));
                uint64_t worst = (uint64_t)__shfl((unsigned long long)w, r * 16, 64);
                if (m >= worst) break;
                unsigned long long holders = __ballot(rloc == r && ent == worst);
                int first = (int)(__ffsll(holders) - 1);
                if (lane == first) ent = m;
                if (lmin == m) {
                    #pragma unroll
                    for (int j = 0; j < 8; ++j) if (kk[j] == m) kk[j] = ~0ull;
                    lmin = kk[0];
                    #pragma unroll
                    for (int j = 1; j < 8; ++j) lmin = u64min(lmin, kk[j]);
                }
            }
        }
    }

    // ---- bitonic sort each 16-lane group ascending (sorts all 4 rows at once) ----
    {
        const int l4 = lane & 15;
        #pragma unroll
        for (int k = 2; k <= 16; k <<= 1) {
            #pragma unroll
            for (int j = k >> 1; j >= 1; j >>= 1) {
                uint64_t o = (uint64_t)__shfl_xor((unsigned long long)ent, j, 64);
                bool up = ((l4 & k) == 0);
                bool keepmin = (((l4 & j) == 0) == up);
                ent = keepmin ? u64min(ent, o) : u64max(ent, o);
            }
        }
    }

    // ---- indices output: rank t (t<8) of row (lane>>4) ----
    if ((lane & 15) < NTOP) {
        int lrow = wid * ROWS_PER_WAVE + rloc;
        int grow = row0 + lrow;
        out[(size_t)NB * ND + (size_t)grow * NTOP + (lane & 15)] =
            (float)(uint32_t)(ent & 0xFFFFFFFFu);
    }

    // ---- softmax + z_q + straight-through + loss (f64 internal; outputs f32) ----
    double loss_local = 0.0;
    for (int r = 0; r < ROWS_PER_WAVE; ++r) {
        const int lrow = wid * ROWS_PER_WAVE + r;
        const int grow = row0 + lrow;
        double e[NTOP], den = 0.0;
        int    it[NTOP];
        uint64_t kb = (uint64_t)__shfl((unsigned long long)ent, r * 16, 64);
        float q0 = unmono_f32((uint32_t)(kb >> 32));
        #pragma unroll
        for (int t = 0; t < NTOP; ++t) {
            uint64_t kt = (uint64_t)__shfl((unsigned long long)ent, r * 16 + t, 64);
            float qt = unmono_f32((uint32_t)(kt >> 32));
            it[t] = (int)(uint32_t)(kt & 0xFFFFFFFFu);
            e[t] = exp((double)q0 - (double)qt);
            den += e[t];
        }
        const int d0 = 2 * lane;
        double zq0 = 0.0, zq1 = 0.0;
        #pragma unroll
        for (int t = 0; t < NTOP; ++t) {
            float2 cv = *reinterpret_cast<const float2*>(&cb[(size_t)it[t] * ND + d0]);
            double w = e[t] / den;
            zq0 += w * (double)cv.x;
            zq1 += w * (double)cv.y;
        }
        #pragma unroll
        for (int t2 = 0; t2 < 2; ++t2) {
            int d = d0 + t2;
            float zf  = zs[lrow][d];
            float zqf = (float)(t2 ? zq1 : zq0);
            out[(size_t)grow * ND + d] = zf + (zqf - zf);   // straight-through (f32 ops)
            double diff = (double)zqf - (double)zf;
            loss_local += diff * diff;
        }
    }

    #pragma unroll
    for (int s = 1; s < 64; s <<= 1) loss_local += __shfl_xor(loss_local, s, 64);
    if (lane == 0) atomicAdd(loss_acc, loss_local);
}

__global__ void vq_finalize(const double* __restrict__ loss_acc, float* __restrict__ out)
{
    out[(size_t)NB * ND + (size_t)NB * NTOP] =
        (float)(1.25 * (*loss_acc) / (double)((size_t)NB * ND));
}

extern "C" void kernel_launch(void* const* d_in, const int* in_sizes, int n_in,
                              void* d_out, int out_size, void* d_ws, size_t ws_size,
                              hipStream_t stream)
{
    const float* z  = (const float*)d_in[0];
    const float* cb = (const float*)d_in[1];
    float* out      = (float*)d_out;
    double* loss    = (double*)d_ws;

    hipMemsetAsync(d_ws, 0, sizeof(double), stream);
    vq_main<<<NB / ROWS_PER_BLOCK, NTHREADS, 0, stream>>>(z, cb, out, loss);
    vq_finalize<<<1, 1, 0, stream>>>(loss, out);
}

// Round 4
// 1186.442 us; speedup vs baseline: 1.1919x; 1.1919x over previous
//
#include <hip/hip_runtime.h>
#include <stdint.h>

#define NB 8192
#define ND 128
#define NK 32768
#define NTOP 8
#define ROWS_PER_BLOCK 32
#define NTHREADS 512
#define NWAVES 8
#define CHUNK 1024
#define NCHUNK (NK / CHUNK)   // 32
#define CT_PITCH 1026         // 1024 + 2 pad: stride % 32 == 2 -> <=2-way (free)

__device__ __forceinline__ uint32_t mono_f32(float f) {
    uint32_t u = __float_as_uint(f);
    return (u & 0x80000000u) ? ~u : (u | 0x80000000u);
}
__device__ __forceinline__ float unmono_f32(uint32_t h) {
    uint32_t u = (h & 0x80000000u) ? (h & 0x7fffffffu) : ~h;
    return __uint_as_float(u);
}
__device__ __forceinline__ uint64_t u64min(uint64_t a, uint64_t b) { return a < b ? a : b; }
__device__ __forceinline__ uint64_t u64max(uint64_t a, uint64_t b) { return a > b ? a : b; }

__global__ __launch_bounds__(NTHREADS, 1)
void vq_main(const float* __restrict__ z, const float* __restrict__ cb,
             float* __restrict__ out, double* __restrict__ loss_acc)
{
    __shared__ float    zs[ROWS_PER_BLOCK][ND];   // 16 KB
    __shared__ float    ct[32 * CT_PITCH];        // 128.25 KB, [d in quarter][code]
    __shared__ float    A_s[ROWS_PER_BLOCK];
    __shared__ uint64_t fin[ROWS_PER_BLOCK][16];  // 4 KB: two top-8 lists per row

    const int tid  = threadIdx.x;
    const int lane = tid & 63;
    const int wid  = tid >> 6;
    const int row0 = blockIdx.x * ROWS_PER_BLOCK;

    // wave ownership: rows rgrp*8..+7, code-half `half` of each chunk
    const int rgrp  = wid & 3;
    const int hbase = (wid >> 2) * 512;

    // ---- stage z tile (coalesced) ----
    #pragma unroll
    for (int i = 0; i < (ROWS_PER_BLOCK * ND) / NTHREADS; ++i) {
        int e = tid + i * NTHREADS;
        zs[e >> 7][e & 127] = z[(size_t)(row0 + (e >> 7)) * ND + (e & 127)];
    }
    __syncthreads();

    // ---- A = numpy-pairwise f32 sum of z*z (bit-exact np.sum replication) ----
    if (lane < 4) {
        const int lrow = wid * 4 + lane;
        float rr[8];
        #pragma unroll
        for (int j = 0; j < 8; ++j) {
            float v = zs[lrow][j];
            float p = v * v;
            asm volatile("" : "+v"(p));   // block fma contraction: a_i rounds first
            rr[j] = p;
        }
        #pragma unroll
        for (int i = 8; i < 128; i += 8) {
            #pragma unroll
            for (int j = 0; j < 8; ++j) {
                float v = zs[lrow][i + j];
                float p = v * v;
                asm volatile("" : "+v"(p));
                rr[j] += p;
            }
        }
        A_s[lrow] = ((rr[0] + rr[1]) + (rr[2] + rr[3])) + ((rr[4] + rr[5]) + (rr[6] + rr[7]));
    }
    __syncthreads();

    // running top-8 per row (UNSORTED): lane holds slot (lane&7) of row (lane>>3)
    uint64_t ent = ~0ull;       // sentinel = +inf
    const int rloc = lane >> 3;

    for (int kc = 0; kc < NCHUNK; ++kc) {
        const int k0 = kc * CHUNK;
        float acc[8][8];
        #pragma unroll
        for (int r = 0; r < 8; ++r)
            #pragma unroll
            for (int j = 0; j < 8; ++j) acc[r][j] = 0.f;

        for (int q = 0; q < 4; ++q) {
            __syncthreads();   // previous quarter's readers done
            // stage 1024 codes x 32 dims, transposed into ct[d][code]
            #pragma unroll
            for (int i = 0; i < 16; ++i) {
                int e4   = tid + i * NTHREADS;   // 0..8191 float4s
                int code = e4 >> 3;              // 0..1023
                int d4   = e4 & 7;               // float4 within 32-d quarter
                const float4 v = *reinterpret_cast<const float4*>(
                    &cb[(size_t)(k0 + code) * ND + q * 32 + d4 * 4]);
                ct[(d4 * 4 + 0) * CT_PITCH + code] = v.x;
                ct[(d4 * 4 + 1) * CT_PITCH + code] = v.y;
                ct[(d4 * 4 + 2) * CT_PITCH + code] = v.z;
                ct[(d4 * 4 + 3) * CT_PITCH + code] = v.w;
            }
            __syncthreads();
            // compute: lane's codes (within half) = 2*lane + (j&1) + 128*(j>>1)
            // dot accumulated as SEQUENTIAL FMA CHAIN in ascending d (exactness)
            #pragma unroll 4
            for (int d = 0; d < 32; ++d) {
                float zv[8];
                #pragma unroll
                for (int r = 0; r < 8; ++r)
                    zv[r] = zs[rgrp * 8 + r][q * 32 + d];   // uniform broadcast
                const float* ctd = &ct[d * CT_PITCH + hbase + 2 * lane];
                #pragma unroll
                for (int jp = 0; jp < 4; ++jp) {
                    float2 cv = *reinterpret_cast<const float2*>(&ctd[128 * jp]);
                    #pragma unroll
                    for (int r = 0; r < 8; ++r) {
                        acc[r][2 * jp + 0] = __builtin_fmaf(zv[r], cv.x, acc[r][2 * jp + 0]);
                        acc[r][2 * jp + 1] = __builtin_fmaf(zv[r], cv.y, acc[r][2 * jp + 1]);
                    }
                }
            }
        }

        // ---- merge chunk candidates into running top-8 (per owned row) ----
        for (int r = 0; r < 8; ++r) {
            const float Ar = A_s[rgrp * 8 + r];
            uint64_t kk[8];
            #pragma unroll
            for (int j = 0; j < 8; ++j) {
                int code = k0 + hbase + 2 * lane + (j & 1) + 128 * (j >> 1);
                float qv = Ar - 2.0f * acc[r][j];   // fl32 == reference d (cc vanishes)
                kk[j] = ((uint64_t)mono_f32(qv) << 32) | (uint32_t)code;
            }
            uint64_t lmin = kk[0];
            #pragma unroll
            for (int j = 1; j < 8; ++j) lmin = u64min(lmin, kk[j]);

            while (true) {
                uint64_t m = lmin;
                #pragma unroll
                for (int s = 1; s < 64; s <<= 1)
                    m = u64min(m, (uint64_t)__shfl_xor((unsigned long long)m, s, 64));
                uint64_t w = ent;   // row-group max over 8-lane group (masks 1,2,4)
                #pragma unroll
                for (int s = 1; s < 8; s <<= 1)
                    w = u64max(w, (uint64_t)__shfl_xor((unsigned long long)w, s, 64));
                uint64_t worst = (uint64_t)__shfl((unsigned long long)w, r * 8, 64);
                if (m >= worst) break;
                unsigned long long holders = __ballot(rloc == r && ent == worst);
                int first = (int)(__ffsll(holders) - 1);
                if (lane == first) ent = m;
                if (lmin == m) {
                    #pragma unroll
                    for (int j = 0; j < 8; ++j) if (kk[j] == m) kk[j] = ~0ull;
                    lmin = kk[0];
                    #pragma unroll
                    for (int j = 1; j < 8; ++j) lmin = u64min(lmin, kk[j]);
                }
            }
        }
    }

    // ---- publish per-wave (half-stream) top-8 lists ----
    fin[rgrp * 8 + rloc][(wid >> 2) * 8 + (lane & 7)] = ent;
    __syncthreads();

    // ---- final: union of 2 half-lists (16 keys) -> bitonic sort -> top-8 ----
    {
        const int row = wid * 4 + (lane >> 4);     // wave handles 4 rows, 16 lanes each
        const int l4  = lane & 15;
        uint64_t key = fin[row][l4];
        #pragma unroll
        for (int k = 2; k <= 16; k <<= 1) {
            #pragma unroll
            for (int j = k >> 1; j >= 1; j >>= 1) {
                uint64_t o = (uint64_t)__shfl_xor((unsigned long long)key, j, 64);
                bool up = ((l4 & k) == 0);
                bool keepmin = (((l4 & j) == 0) == up);
                key = keepmin ? u64min(key, o) : u64max(key, o);
            }
        }
        fin[row][l4] = key;    // sorted ascending; ranks 0..7 = final top-8
        if (l4 < NTOP) {
            int grow = row0 + row;
            out[(size_t)NB * ND + (size_t)grow * NTOP + l4] =
                (float)(uint32_t)(key & 0xFFFFFFFFu);
        }
    }
    __syncthreads();

    // ---- softmax + z_q + straight-through + loss (f64 internal; outputs f32) ----
    double loss_local = 0.0;
    for (int r2 = 0; r2 < 4; ++r2) {
        const int lrow = wid * 4 + r2;
        const int grow = row0 + lrow;
        double e[NTOP], den = 0.0;
        int    it[NTOP];
        float q0 = unmono_f32((uint32_t)(fin[lrow][0] >> 32));
        #pragma unroll
        for (int t = 0; t < NTOP; ++t) {
            uint64_t kt = fin[lrow][t];
            float qt = unmono_f32((uint32_t)(kt >> 32));
            it[t] = (int)(uint32_t)(kt & 0xFFFFFFFFu);
            e[t] = exp((double)q0 - (double)qt);
            den += e[t];
        }
        const int d0 = 2 * lane;
        double zq0 = 0.0, zq1 = 0.0;
        #pragma unroll
        for (int t = 0; t < NTOP; ++t) {
            float2 cv = *reinterpret_cast<const float2*>(&cb[(size_t)it[t] * ND + d0]);
            double w = e[t] / den;
            zq0 += w * (double)cv.x;
            zq1 += w * (double)cv.y;
        }
        #pragma unroll
        for (int t2 = 0; t2 < 2; ++t2) {
            int d = d0 + t2;
            float zf  = zs[lrow][d];
            float zqf = (float)(t2 ? zq1 : zq0);
            out[(size_t)grow * ND + d] = zf + (zqf - zf);   // straight-through (f32 ops)
            double diff = (double)zqf - (double)zf;
            loss_local += diff * diff;
        }
    }

    #pragma unroll
    for (int s = 1; s < 64; s <<= 1) loss_local += __shfl_xor(loss_local, s, 64);
    if (lane == 0) atomicAdd(loss_acc, loss_local);
}

__global__ void vq_finalize(const double* __restrict__ loss_acc, float* __restrict__ out)
{
    out[(size_t)NB * ND + (size_t)NB * NTOP] =
        (float)(1.25 * (*loss_acc) / (double)((size_t)NB * ND));
}

extern "C" void kernel_launch(void* const* d_in, const int* in_sizes, int n_in,
                              void* d_out, int out_size, void* d_ws, size_t ws_size,
                              hipStream_t stream)
{
    const float* z  = (const float*)d_in[0];
    const float* cb = (const float*)d_in[1];
    float* out      = (float*)d_out;
    double* loss    = (double*)d_ws;

    hipMemsetAsync(d_ws, 0, sizeof(double), stream);
    vq_main<<<NB / ROWS_PER_BLOCK, NTHREADS, 0, stream>>>(z, cb, out, loss);
    vq_finalize<<<1, 1, 0, stream>>>(loss, out);
}